// Round 4
// baseline (189.462 us; speedup 1.0000x reference)
//
#include <hip/hip_runtime.h>
#include <hip/hip_bf16.h>

// Problem constants (reference: B=2048, F=512, U=512, G=64, REG_STRENGTH=1.0)
#define B_SZ 2048
#define F_SZ 512
#define U_SZ 512
#define G_SZ 64
#define REG_STRENGTH 1.0f

// Streaming MFMA grouped GEMM, NO LDS, NO barriers.
// Wave tile: 64 rows (4 A-subtiles) x 16 cols (1 B-frag), K=512 in 16 steps.
// Block = 4 independent waves covering 64 u-cols. Grid (8 u-strips, 96 chunks).
#define BM 64
#define NXT (U_SZ / 64)              // 8 blocks in u
#define MAXCH 96                     // worst-case chunk slots (2048/64 + 63)

typedef __attribute__((ext_vector_type(8))) short bf16x8;  // 8 bf16 = 4 VGPR
typedef __attribute__((ext_vector_type(4))) float f32x4;

// Workspace int layout
#define WS_WSF      0   // float: weighted (w+b) reg-loss accumulator
#define WS_TICKET   1
#define WS_NCH      2
#define WS_COUNTS   4
#define WS_ROWSTART (4 + G_SZ)
#define WS_ORDER    (4 + 2 * G_SZ)
#define WS_CHUNKS   (4 + 2 * G_SZ + B_SZ)

// f32 pair -> packed bf16 pair (RNE), 5 VALU ops per 2 values.
__device__ __forceinline__ unsigned rnepack(float lo, float hi) {
  unsigned a = __float_as_uint(lo), b = __float_as_uint(hi);
  a += 0x7FFFu + ((a >> 16) & 1u);
  b += 0x7FFFu + ((b >> 16) & 1u);
  // result = (hi16 of b) << 16 | (hi16 of a)
  return __builtin_amdgcn_perm(b, a, 0x07060302);
}

__device__ __forceinline__ bf16x8 cvt8(float4 p, float4 q) {
  union { unsigned u[4]; bf16x8 v; } r;
  r.u[0] = rnepack(p.x, p.y);
  r.u[1] = rnepack(p.z, p.w);
  r.u[2] = rnepack(q.x, q.y);
  r.u[3] = rnepack(q.z, q.w);
  return r.v;
}

// ---------------------------------------------------------------------------
// Kernel A: histogram gid -> counts, prefix -> rowstart, scatter -> order,
// build BM-row chunk worklist. Zero wsf/ticket.
// ---------------------------------------------------------------------------
__global__ __launch_bounds__(1024) void prep_kernel(
    const int* __restrict__ gid, int* __restrict__ wsi) {
  __shared__ int cnt_s[G_SZ];
  __shared__ int cur_s[G_SZ];
  __shared__ int chk_s[G_SZ];
  const int tid = threadIdx.x;

  if (tid < G_SZ) cnt_s[tid] = 0;
  if (tid == 0) { ((float*)wsi)[WS_WSF] = 0.0f; wsi[WS_TICKET] = 0; }
  __syncthreads();

  for (int b = tid; b < B_SZ; b += 1024) atomicAdd(&cnt_s[gid[b]], 1);
  __syncthreads();

  if (tid == 0) {
    int run = 0, crun = 0;
    for (int g = 0; g < G_SZ; ++g) {
      cur_s[g] = run;
      chk_s[g] = crun;
      run += cnt_s[g];
      crun += (cnt_s[g] + BM - 1) / BM;
    }
    wsi[WS_NCH] = crun;
  }
  __syncthreads();

  if (tid < G_SZ) {
    wsi[WS_COUNTS + tid] = cnt_s[tid];
    wsi[WS_ROWSTART + tid] = cur_s[tid];
    const int nch = (cnt_s[tid] + BM - 1) / BM;
    const int cs = chk_s[tid];
    for (int i = 0; i < nch; ++i)
      wsi[WS_CHUNKS + cs + i] = tid | ((i * BM) << 8);  // g | (r0<<8)
  }
  __syncthreads();  // rowstart snapshot before scatter mutates cur_s

  for (int b = tid; b < B_SZ; b += 1024) {
    int pos = atomicAdd(&cur_s[gid[b]], 1);
    wsi[WS_ORDER + pos] = b;
  }
}

// ---------------------------------------------------------------------------
// Kernel B: barrier-free streaming bf16-MFMA grouped GEMM.
// block = (u-strip x, chunk slot y); wave w covers cols [x*64+16w, +16).
// Each lane loads its MFMA fragments directly from global (8 contiguous f32
// = 2 dwordx4), converts to bf16 in registers, accumulates 4 subtile MFMAs
// per 32-wide K step. Fuses the W reg loss (f32, pre-conversion) on r0==0
// chunks and the b-loss in the epilogue; ticket block writes the scalar.
// ---------------------------------------------------------------------------
__global__ __launch_bounds__(256, 2) void gemm_kernel(
    const float* __restrict__ x, const float* __restrict__ w_mu,
    const float* __restrict__ b_mu, const float* __restrict__ w0_mu,
    const float* __restrict__ b0_mu, float* __restrict__ out,
    int* __restrict__ wsi) {
  const int tid = threadIdx.x;
  const int lane = tid & 63;
  const int wave = tid >> 6;
  const int fl = lane & 15;   // A row / B col within subtile
  const int fq = lane >> 4;   // quad: input k-block = fq*8; output row = fq*4+i
  const int slot = blockIdx.y;
  const int nch = wsi[WS_NCH];

  if (slot < nch) {
    const int entry = wsi[WS_CHUNKS + slot];
    const int g = entry & 0xFF;
    const int r0 = entry >> 8;
    const int cnt = wsi[WS_COUNTS + g];
    const int rs = wsi[WS_ROWSTART + g];
    const int ucol = blockIdx.x * 64 + wave * 16 + fl;  // this lane's B col
    const bool do_reg = (r0 == 0);
    float regp = 0.0f;

    // Fragment base pointers (fq*8 k-offset folded in)
    const float* __restrict__ wrow =
        w_mu + ((size_t)g * U_SZ + ucol) * F_SZ + fq * 8;
    const float* __restrict__ w0row = w0_mu + (size_t)ucol * F_SZ + fq * 8;
    const float* xrow[4];
#pragma unroll
    for (int mt = 0; mt < 4; ++mt) {
      int r = r0 + mt * 16 + fl;
      if (r >= cnt) r = cnt - 1;  // clamp; padded rows never stored
      xrow[mt] = x + (size_t)wsi[WS_ORDER + rs + r] * F_SZ + fq * 8;
    }

    f32x4 acc[4] = {{0.f, 0.f, 0.f, 0.f}, {0.f, 0.f, 0.f, 0.f},
                    {0.f, 0.f, 0.f, 0.f}, {0.f, 0.f, 0.f, 0.f}};

#pragma unroll 2
    for (int kc = 0; kc < F_SZ; kc += 32) {
      // B fragment: 8 contiguous f32 of this lane's W row
      const float4 wa = *(const float4*)(wrow + kc);
      const float4 wb = *(const float4*)(wrow + kc + 4);
      if (do_reg) {  // fused W reg loss on exact f32 values
        const float4 za = *(const float4*)(w0row + kc);
        const float4 zb = *(const float4*)(w0row + kc + 4);
        float d0 = wa.x - za.x, d1 = wa.y - za.y, d2 = wa.z - za.z,
              d3 = wa.w - za.w, d4 = wb.x - zb.x, d5 = wb.y - zb.y,
              d6 = wb.z - zb.z, d7 = wb.w - zb.w;
        regp += d0 * d0 + d1 * d1 + d2 * d2 + d3 * d3 + d4 * d4 + d5 * d5 +
                d6 * d6 + d7 * d7;
      }
      const bf16x8 bfrag = cvt8(wa, wb);
#pragma unroll
      for (int mt = 0; mt < 4; ++mt) {
        const float4 xa = *(const float4*)(xrow[mt] + kc);
        const float4 xb = *(const float4*)(xrow[mt] + kc + 4);
        const bf16x8 afrag = cvt8(xa, xb);
        acc[mt] =
            __builtin_amdgcn_mfma_f32_16x16x32_bf16(afrag, bfrag, acc[mt], 0, 0, 0);
      }
    }

    // Epilogue: bias + fused b-loss, scatter to original batch rows.
    const float bias = b_mu[(g << 9) + ucol];
    if (do_reg && fq == 0) {  // count each (g,u) bias exactly once
      const float d = bias - b0_mu[ucol];
      regp += d * d;
    }
#pragma unroll
    for (int mt = 0; mt < 4; ++mt) {
#pragma unroll
      for (int i = 0; i < 4; ++i) {
        const int r = r0 + mt * 16 + fq * 4 + i;
        if (r < cnt) {
          const int brow = wsi[WS_ORDER + rs + r];
          out[(size_t)brow * U_SZ + ucol] = acc[mt][i] + bias;
        }
      }
    }

    // Wave-reduce reg partials, weight by count, one atomic per wave.
    if (do_reg) {
#pragma unroll
      for (int off = 32; off > 0; off >>= 1) regp += __shfl_down(regp, off);
      if (lane == 0) atomicAdd((float*)&wsi[WS_WSF], (float)cnt * regp);
    }
  }

  // Ticket: last block overall writes the scalar reg loss.
  __threadfence();
  if (tid == 0) {
    if (atomicAdd(&wsi[WS_TICKET], 1) == (int)(gridDim.x * gridDim.y) - 1) {
      float v = atomicAdd((float*)&wsi[WS_WSF], 0.0f);  // coherent read
      out[(size_t)B_SZ * U_SZ] = REG_STRENGTH * v;
    }
  }
}

extern "C" void kernel_launch(void* const* d_in, const int* in_sizes, int n_in,
                              void* d_out, int out_size, void* d_ws, size_t ws_size,
                              hipStream_t stream) {
  const float* x     = (const float*)d_in[0];
  const int*   gid   = (const int*)d_in[1];
  const float* w_mu  = (const float*)d_in[2];
  const float* b_mu  = (const float*)d_in[3];
  const float* w0_mu = (const float*)d_in[4];
  const float* b0_mu = (const float*)d_in[5];
  float* out = (float*)d_out;
  int* wsi = (int*)d_ws;

  prep_kernel<<<1, 1024, 0, stream>>>(gid, wsi);
  gemm_kernel<<<dim3(NXT, MAXCH), 256, 0, stream>>>(
      x, w_mu, b_mu, w0_mu, b0_mu, out, wsi);
}